// Round 21
// baseline (2012.841 us; speedup 1.0000x reference)
//
#include <hip/hip_runtime.h>
#include <hip/hip_bf16.h>

#define L_   2048
#define NB_  512
#define HID_ 1024
#define H_   16
#define D_   64
#define B_   8
#define Q_   2048

typedef unsigned short u16;
typedef float  f32x4  __attribute__((ext_vector_type(4)));
typedef short  short8 __attribute__((ext_vector_type(8)));

__device__ __forceinline__ u16 f2b_d21(float x) {
    __hip_bfloat16 h = __float2bfloat16(x);
    union { __hip_bfloat16 h; u16 u; } cv; cv.h = h; return cv.u;
}
__device__ __forceinline__ float b2f_d21(u16 u) {
    union { u16 u; __hip_bfloat16 h; } cv; cv.u = u; return __bfloat162float(cv.h);
}
__device__ __forceinline__ float ldin_d21(const void* p, long i, int bf) {
    return bf ? b2f_d21(((const u16*)p)[i]) : ((const float*)p)[i];
}

#define GLDSD21(gp, lp) __builtin_amdgcn_global_load_lds( \
    (const __attribute__((address_space(1))) void*)(gp), \
    (__attribute__((address_space(3))) void*)(lp), 16, 0, 0)

// ---------------------------------------------------------------------------
__global__ void probe_d21(const unsigned* __restrict__ k, int* __restrict__ flag)
{
    __shared__ int cnt;
    if (threadIdx.x == 0) cnt = 0;
    __syncthreads();
    int c = 0;
    for (int i = threadIdx.x; i < 4096; i += 256) {
        unsigned e = (k[i] >> 7) & 0xFFu;
        if (e >= 100u && e <= 135u) c++;
    }
    atomicAdd(&cnt, c);
    __syncthreads();
    if (threadIdx.x == 0) *flag = (cnt > 2048) ? 1 : 0;
}

__global__ void beacon_d21(float* __restrict__ out, long n, float code)
{
    long i = (long)blockIdx.x * blockDim.x + threadIdx.x;
    long st = (long)gridDim.x * blockDim.x;
    for (; i < n; i += st) out[i] = 0.f;
    if (blockIdx.x == 0 && threadIdx.x == 0) out[0] = code;
}

// ---------------------------------------------------------------------------
__global__ void conv_d21(const void* __restrict__ in, u16* __restrict__ out,
                         long n, const int* __restrict__ dflag)
{
    const int bf = *dflag;
    long i = (long)blockIdx.x * blockDim.x + threadIdx.x;
    long st = (long)gridDim.x * blockDim.x;
    for (; i < n; i += st) out[i] = f2b_d21(ldin_d21(in, i, bf));
}

// query (B,H,Q,64) -> qflat (B,Q,HID) bf16
__global__ void qg_d21(const void* __restrict__ q, u16* __restrict__ out,
                       const int* __restrict__ dflag)
{
    const int bf = *dflag;
    const long n = (long)B_ * H_ * Q_ * D_;
    long i = (long)blockIdx.x * blockDim.x + threadIdx.x;
    long st = (long)gridDim.x * blockDim.x;
    for (; i < n; i += st) {
        long dd = i & 63; long t = i >> 6;
        long qq = t & (Q_ - 1); t >>= 11;
        long h = t & (H_ - 1); long b = t >> 4;
        out[(b * Q_ + qq) * HID_ + h * 64 + dd] = f2b_d21(ldin_d21(q, i, bf));
    }
}

// fp32 -> hi + lo residual (bf16)   [proven]
__global__ void split_d21(const float* __restrict__ in, u16* __restrict__ hi,
                          u16* __restrict__ lo, long n)
{
    long i = (long)blockIdx.x * blockDim.x + threadIdx.x;
    long st = (long)gridDim.x * blockDim.x;
    for (; i < n; i += st) {
        float v = in[i];
        u16 h = f2b_d21(v);
        hi[i] = h;
        lo[i] = f2b_d21(v - b2f_d21(h));
    }
}

// transpose (proven): in (R,C) raw -> out (C,R) bf16
__global__ __launch_bounds__(256)
void tr_d21(const void* __restrict__ in, u16* __restrict__ out,
            int R, int C, long sIn, long sOut, const int* __restrict__ dflag)
{
    const int bf = *dflag;
    __shared__ u16 t[64][66];
    const long ibase = (long)blockIdx.z * sIn;
    u16* ob = out + (long)blockIdx.z * sOut;
    const int r0 = blockIdx.y * 64, c0 = blockIdx.x * 64;
    const int lc = threadIdx.x & 63, rb = threadIdx.x >> 6;
    #pragma unroll
    for (int kk = 0; kk < 16; ++kk) {
        int r = rb * 16 + kk;
        t[r][lc] = f2b_d21(ldin_d21(in, ibase + (long)(r0 + r) * C + c0 + lc, bf));
    }
    __syncthreads();
    #pragma unroll
    for (int kk = 0; kk < 16; ++kk) {
        int cr = rb * 16 + kk;
        ob[(long)(c0 + cr) * R + r0 + lc] = t[lc][cr];
    }
}

// elementwise mask epilogue (proven): km = kT * sigmoid(S + bmask), in place
__global__ void ew_d21(float* __restrict__ S, const u16* __restrict__ kT,
                       const void* __restrict__ bmask, const int* __restrict__ dflag)
{
    const int bf = *dflag;
    const long n = (long)B_ * HID_ * L_;
    long i = (long)blockIdx.x * blockDim.x + threadIdx.x;
    long st = (long)gridDim.x * blockDim.x;
    for (; i < n; i += st) {
        long m = i & (L_ - 1);
        float sg = 1.f / (1.f + expf(-(S[i] + ldin_d21(bmask, m, bf))));
        S[i] = b2f_d21(kT[i]) * sg;
    }
}

// ---------------------------------------------------------------------------
// MFMA GEMM (m97 structure, proven): C[M,N] = sum_k A[M,K]*Bt[N,K]
// epi: 3 = fp32 store (scale applied) ; 4 = fp32 accumulate
// ---------------------------------------------------------------------------
__global__ __launch_bounds__(256)
void gemm_d21(const u16* __restrict__ A, int lda, long sA,
              const u16* __restrict__ Bt, int ldb, long sB,
              float* __restrict__ Cv, int ldc, long sC, int K,
              float scale, int epi)
{
    __shared__ u16 As[128 * 32];
    __shared__ u16 Bs[128 * 32];
    const int tid = threadIdx.x;
    const int wv = tid >> 6, ln = tid & 63;
    const int g = ln >> 4, lr = ln & 15;
    const int wr = wv >> 1, wc = wv & 1;
    const int bm = blockIdx.y * 128, bn = blockIdx.x * 128;
    const u16* Ab = A + (long)blockIdx.z * sA;
    const u16* Bb = Bt + (long)blockIdx.z * sB;

    const int sr = ln >> 2;
    const int scl = (ln & 3) * 8;
    const u16* ga0 = Ab + (long)(bm + wv * 16 + sr) * lda + scl;
    const u16* ga1 = Ab + (long)(bm + (wv + 4) * 16 + sr) * lda + scl;
    const u16* gb0 = Bb + (long)(bn + wv * 16 + sr) * ldb + scl;
    const u16* gb1 = Bb + (long)(bn + (wv + 4) * 16 + sr) * ldb + scl;
    u16* la0 = &As[wv * 512];
    u16* la1 = &As[(wv + 4) * 512];
    u16* lb0 = &Bs[wv * 512];
    u16* lb1 = &Bs[(wv + 4) * 512];

    f32x4 acc[4][4];
    #pragma unroll
    for (int i = 0; i < 4; ++i)
        #pragma unroll
        for (int j = 0; j < 4; ++j) acc[i][j] = (f32x4){0.f, 0.f, 0.f, 0.f};

    for (int k0 = 0; k0 < K; k0 += 32) {
        GLDSD21(ga0 + k0, la0);
        GLDSD21(ga1 + k0, la1);
        GLDSD21(gb0 + k0, lb0);
        GLDSD21(gb1 + k0, lb1);
        __syncthreads();
        short8 af[4], bfr[4];
        #pragma unroll
        for (int i = 0; i < 4; ++i) af[i] = *(const short8*)&As[(wr * 64 + i * 16 + lr) * 32 + g * 8];
        #pragma unroll
        for (int j = 0; j < 4; ++j) bfr[j] = *(const short8*)&Bs[(wc * 64 + j * 16 + lr) * 32 + g * 8];
        #pragma unroll
        for (int i = 0; i < 4; ++i)
            #pragma unroll
            for (int j = 0; j < 4; ++j)
                acc[i][j] = __builtin_amdgcn_mfma_f32_16x16x32_bf16(af[i], bfr[j], acc[i][j], 0, 0, 0);
        __syncthreads();
    }

    // C/D layout (r4-verified): col = lane&15, row = (lane>>4)*4 + reg
    const int r0 = bm + wr * 64 + g * 4;
    const int c0 = bn + wc * 64 + lr;
    float* C = Cv + (long)blockIdx.z * sC;
    #pragma unroll
    for (int i = 0; i < 4; ++i)
        #pragma unroll
        for (int j = 0; j < 4; ++j)
            #pragma unroll
            for (int r = 0; r < 4; ++r) {
                long o = (long)(r0 + i * 16 + r) * ldc + (c0 + j * 16);
                if (epi == 4) C[o] += acc[i][j][r];
                else          C[o] = scale * acc[i][j][r];
            }
}

// ---------------------------------------------------------------------------
// G2 scalar, 128x128 tile, 8x8 acc per thread (fp32, same l-order as r18 sg2)
// Bmat[b][n][c] = sum_l gs[l][n] * km[b][c][l]
// ---------------------------------------------------------------------------
__global__ __launch_bounds__(256)
void sg2b_d21(const float* __restrict__ kmF, const void* __restrict__ gs,
              float* __restrict__ BmatF, const int* __restrict__ dflag)
{
    const int bf = *dflag;
    __shared__ float gst[32][129];   // [l_off][n_off]
    __shared__ float kmt[128][33];   // [c_off][l_off]
    const int b = blockIdx.z;
    const int c0 = blockIdx.x * 128, n0 = blockIdx.y * 128;
    const int tid = threadIdx.x;
    const int tx = tid & 15, ty = tid >> 4;      // outputs: c = c0+tx+16i, n = n0+ty+16j
    float acc[8][8];
    #pragma unroll
    for (int i = 0; i < 8; ++i)
        #pragma unroll
        for (int j = 0; j < 8; ++j) acc[i][j] = 0.f;

    const int glc = tid & 127, grb = tid >> 7;   // gst loader
    const int klc = tid & 31,  krb = tid >> 5;   // kmt loader
    for (int l0 = 0; l0 < L_; l0 += 32) {
        #pragma unroll
        for (int kk = 0; kk < 16; ++kk) {
            int r = grb + 2 * kk;                // [0,32)
            gst[r][glc] = ldin_d21(gs, (long)(l0 + r) * NB_ + n0 + glc, bf);
            int rr = krb + 8 * kk;               // [0,128)
            kmt[rr][klc] = kmF[((long)b * HID_ + c0 + rr) * L_ + l0 + klc];
        }
        __syncthreads();
        #pragma unroll 4
        for (int kk = 0; kk < 32; ++kk) {
            float gv[8], kv[8];
            #pragma unroll
            for (int j = 0; j < 8; ++j) gv[j] = gst[kk][ty + 16 * j];
            #pragma unroll
            for (int i = 0; i < 8; ++i) kv[i] = kmt[tx + 16 * i][kk];
            #pragma unroll
            for (int i = 0; i < 8; ++i)
                #pragma unroll
                for (int j = 0; j < 8; ++j)
                    acc[i][j] += kv[i] * gv[j];
        }
        __syncthreads();
    }
    #pragma unroll
    for (int j = 0; j < 8; ++j)
        #pragma unroll
        for (int i = 0; i < 8; ++i)
            BmatF[((long)b * NB_ + n0 + ty + 16 * j) * HID_ + c0 + tx + 16 * i] = acc[i][j];
}

// ---------------------------------------------------------------------------
// hoisted score reductions (proven verbatim)
// ---------------------------------------------------------------------------
__global__ void kw_d21(const float* __restrict__ keysF,
                       const void* __restrict__ w_mu, const void* __restrict__ w_sg,
                       float* __restrict__ kwmu, float* __restrict__ kwsg,
                       const int* __restrict__ dflag)
{
    const int bf = *dflag;
    const int bh = blockIdx.x;
    const int b = bh >> 4, h = bh & 15;
    const int d = threadIdx.x;
    const float* kb = keysF + (long)b * NB_ * HID_ + h * 64 + d;
    float am = 0.f, as = 0.f;
    for (int n = 0; n < NB_; ++n) {
        float kv = kb[(long)n * HID_];
        am += ldin_d21(w_mu, n, bf) * kv;
        as += ldin_d21(w_sg, n, bf) * kv;
    }
    kwmu[(long)bh * 64 + d] = am;
    kwsg[(long)bh * 64 + d] = as;
}

// ---------------------------------------------------------------------------
// attention (proven verbatim; fp32 qh in / ctx out in place)
// ---------------------------------------------------------------------------
__global__ __launch_bounds__(256)
void attn_d21(float* __restrict__ qh, const float* __restrict__ valsF,
              const float* __restrict__ kwmu, const float* __restrict__ kwsg,
              const void* __restrict__ bmu, const void* __restrict__ bsg,
              const int* __restrict__ dflag)
{
    const int bf = *dflag;
    __shared__ float bmuS[512], bvS[512];
    __shared__ float rS[16][512];
    const int b = blockIdx.z, h = blockIdx.y;
    const int tid = threadIdx.x, wv = tid >> 6, lane = tid & 63;

    for (int i = tid; i < 512; i += 256) {
        bmuS[i] = ldin_d21(bmu, i, bf);
        float s = ldin_d21(bsg, i, bf);
        bvS[i] = s * s;
    }
    __syncthreads();

    const int q0 = blockIdx.x * 16 + wv * 4;
    const float km = kwmu[((long)b * H_ + h) * 64 + lane];
    const float ks = kwsg[((long)b * H_ + h) * 64 + lane];

    float qv[4], mu[4], sq[4];
    float* qrow[4];
    #pragma unroll
    for (int j = 0; j < 4; ++j) {
        qrow[j] = qh + ((long)b * Q_ + q0 + j) * HID_ + h * 64;
        qv[j] = qrow[j][lane];
        float pm = qv[j] * km, ps = qv[j] * ks;
        #pragma unroll
        for (int off = 32; off > 0; off >>= 1) {
            pm += __shfl_xor(pm, off);
            ps += __shfl_xor(ps, off);
        }
        mu[j] = 1.f / (1.f + expf(-pm));
        float sp = (ps > 0.f) ? (ps + log1pf(expf(-ps))) : log1pf(expf(ps));
        sq[j] = fmaxf(sp, 1e-6f);
    }

    #pragma unroll
    for (int j = 0; j < 4; ++j) {
        #pragma unroll
        for (int jj = 0; jj < 8; ++jj) {
            int n = lane + 64 * jj;
            float var = sq[j] + bvS[n];
            float dd = mu[j] - bmuS[n];
            rS[wv * 4 + j][n] = expf(-0.5f * dd * dd / var)
                                / sqrtf(6.283185307179586f * var);
        }
    }
    __syncthreads();

    const float* vb = valsF + (long)b * NB_ * HID_ + h * 64 + lane;
    float cd[4] = {0.f, 0.f, 0.f, 0.f};
    for (int n = 0; n < 512; ++n) {
        float v = vb[(long)n * HID_];
        #pragma unroll
        for (int j = 0; j < 4; ++j)
            cd[j] += rS[wv * 4 + j][n] * v;
    }
    #pragma unroll
    for (int j = 0; j < 4; ++j)
        qrow[j][lane] = cd[j];
}

// ---------------------------------------------------------------------------
extern "C" void kernel_launch(void* const* d_in, const int* in_sizes, int n_in,
                              void* d_out, int out_size, void* d_ws, size_t ws_size,
                              hipStream_t stream)
{
    static const int SZ_INS[13] = {16777216,16777216,4194304,2048,1048576,1048576,
                                   1048576,1048576,512,512,1048576,512,512};
    bool mi = (n_in == 13);
    if (mi) for (int i = 0; i < 13; ++i) if (in_sizes[i] != SZ_INS[i]) { mi = false; break; }
    if (!mi) {
        beacon_d21<<<2048, 256, 0, stream>>>((float*)d_out, (long)out_size, 7777777.f);
        return;
    }

    const void* k_in  = d_in[0];
    const void* query = d_in[1];
    const void* wm_f  = d_in[2];
    const void* bmask = d_in[3];
    const void* wq_f  = d_in[4];
    const void* wk_f  = d_in[5];
    const void* wv_f  = d_in[6];
    const void* wo_f  = d_in[7];
    const void* w_mu  = d_in[8];
    const void* w_sg  = d_in[9];
    const void* gs_f  = d_in[10];
    const void* bmu   = d_in[11];
    const void* bsg   = d_in[12];

    char* ws = (char*)d_ws;
    size_t off = 0;
    auto alloc = [&](size_t bytes) { char* p = ws + off; off += (bytes + 255) & ~(size_t)255; return p; };
    const size_t MiB = 1048576;
    const long SBH = (long)NB_ * HID_;
    const long SQH = (long)Q_ * HID_;
    const long SHL = (long)HID_ * L_;
    int*   dflag = (int*)alloc(256);
    char*  RQ    = alloc(64 * MiB);          // wmask[0:8)+kT[8:40) -> qhF/ctxF
    char*  SC    = alloc(64 * MiB);          // scores/kmF -> qflat[0:32)+bmh[32:40)+bml[40:48) -> ctxh/ctxl
    char*  BK    = alloc(16 * MiB);          // BmatF -> keysF
    float* valsF = (float*)alloc(16 * MiB);  // vals -> woc (after attn)
    u16*   wqc   = (u16*)alloc((size_t)HID_ * HID_ * 2);
    u16*   wkc   = (u16*)alloc((size_t)HID_ * HID_ * 2);
    u16*   wvc   = (u16*)alloc((size_t)HID_ * HID_ * 2);
    float* kwmu  = (float*)alloc((size_t)B_ * H_ * 64 * 4);
    float* kwsg  = (float*)alloc((size_t)B_ * H_ * 64 * 4);
    if (ws_size < off) {
        beacon_d21<<<2048, 256, 0, stream>>>((float*)d_out, (long)out_size, 9999999.f);
        return;
    }
    u16*   wmask = (u16*)RQ;                     // [0, 8MiB)
    u16*   kTp   = (u16*)(RQ + 8 * MiB);         // [8, 40MiB)
    float* qhF   = (float*)RQ;                   // after G1/ew (wmask,kT dead)
    float* ctxF  = qhF;
    float* SCf   = (float*)SC;                   // scores -> kmF (in place)
    u16*   qflat = (u16*)SC;                     // [0, 32MiB)   after sg2b
    u16*   bmh   = (u16*)(SC + 32 * MiB);        // [32, 40MiB)
    u16*   bml   = (u16*)(SC + 40 * MiB);        // [40, 48MiB)
    u16*   ctxh  = (u16*)SC;                     // [0, 32MiB)   after attn
    u16*   ctxl  = (u16*)(SC + 32 * MiB);        // [32, 64MiB)
    float* BmatF = (float*)BK;
    float* keysF = (float*)BK;                   // after split (BmatF dead)
    u16*   woc   = (u16*)valsF;                  // after attn (valsF dead)

    probe_d21<<<1, 256, 0, stream>>>((const unsigned*)k_in, dflag);
    conv_d21<<<1024, 256, 0, stream>>>(wq_f, wqc, (long)HID_ * HID_, dflag);
    conv_d21<<<1024, 256, 0, stream>>>(wk_f, wkc, (long)HID_ * HID_, dflag);
    conv_d21<<<1024, 256, 0, stream>>>(wv_f, wvc, (long)HID_ * HID_, dflag);
    conv_d21<<<2048, 256, 0, stream>>>(wm_f, wmask, (long)L_ * L_, dflag);
    tr_d21<<<dim3(HID_ / 64, L_ / 64, B_), 256, 0, stream>>>(
        k_in, kTp, L_, HID_, (long)L_ * HID_, SHL, dflag);

    // G1a (MFMA, proven): SC = kT @ wmask^T  (fp32 scores)
    gemm_d21<<<dim3(L_ / 128, HID_ / 128, B_), 256, 0, stream>>>(
        kTp, L_, SHL, wmask, L_, 0, SCf, L_, SHL, L_, 1.f, 3);
    // G1b (proven): km = kT * sigmoid(SC + bmask)  (in place)
    ew_d21<<<2048, 256, 0, stream>>>(SCf, kTp, bmask, dflag);

    // G2 (scalar fp32, NEW 128x128 tile): BmatF = Gs^T @ km
    sg2b_d21<<<dim3(HID_ / 128, NB_ / 128, B_), 256, 0, stream>>>(SCf, gs_f, BmatF, dflag);
    // split Bmat -> bmh/bml (kmF dead; writes SC[32:48))
    split_d21<<<2048, 256, 0, stream>>>(BmatF, bmh, bml, (long)B_ * SBH);

    // qflat gather into SC[0:32)
    qg_d21<<<4096, 256, 0, stream>>>(query, qflat, dflag);
    // G5 (MFMA, proven): qhF = 0.125 * qflat @ Wq^T  (over RQ; wmask/kT dead)
    gemm_d21<<<dim3(HID_ / 128, Q_ / 128, B_), 256, 0, stream>>>(
        qflat, HID_, SQH, wqc, HID_, 0, qhF, HID_, SQH, HID_, 0.125f, 3);

    // G3 (MFMA 2-pass, proven): keysF = bmh@Wk^T += bml@Wk^T  (over dead BmatF)
    gemm_d21<<<dim3(HID_ / 128, NB_ / 128, B_), 256, 0, stream>>>(
        bmh, HID_, SBH, wkc, HID_, 0, keysF, HID_, SBH, HID_, 1.f, 3);
    gemm_d21<<<dim3(HID_ / 128, NB_ / 128, B_), 256, 0, stream>>>(
        bml, HID_, SBH, wkc, HID_, 0, keysF, HID_, SBH, HID_, 1.f, 4);
    kw_d21<<<B_ * H_, 64, 0, stream>>>(keysF, w_mu, w_sg, kwmu, kwsg, dflag);

    // G4 (MFMA 2-pass, proven): valsF = bmh@Wv^T += bml@Wv^T
    gemm_d21<<<dim3(HID_ / 128, NB_ / 128, B_), 256, 0, stream>>>(
        bmh, HID_, SBH, wvc, HID_, 0, valsF, HID_, SBH, HID_, 1.f, 3);
    gemm_d21<<<dim3(HID_ / 128, NB_ / 128, B_), 256, 0, stream>>>(
        bml, HID_, SBH, wvc, HID_, 0, valsF, HID_, SBH, HID_, 1.f, 4);

    // attention (proven): ctx in place over qhF
    attn_d21<<<dim3(Q_ / 16, H_, B_), 256, 0, stream>>>(
        qhF, valsF, kwmu, kwsg, bmu, bsg, dflag);

    // G7 (MFMA 2-pass, proven): split ctx, out = ctxh@Wo^T += ctxl@Wo^T
    conv_d21<<<1024, 256, 0, stream>>>(wo_f, woc, (long)HID_ * HID_, dflag);
    split_d21<<<2048, 256, 0, stream>>>(ctxF, ctxh, ctxl, (long)B_ * SQH);
    gemm_d21<<<dim3(HID_ / 128, Q_ / 128, B_), 256, 0, stream>>>(
        ctxh, HID_, SQH, woc, HID_, 0, (float*)d_out, HID_, SQH, HID_, 1.f, 3);
    gemm_d21<<<dim3(HID_ / 128, Q_ / 128, B_), 256, 0, stream>>>(
        ctxl, HID_, SQH, woc, HID_, 0, (float*)d_out, HID_, SQH, HID_, 1.f, 4);
}

// Round 22
// 1592.169 us; speedup vs baseline: 1.2642x; 1.2642x over previous
//
#include <hip/hip_runtime.h>
#include <hip/hip_bf16.h>

#define L_   2048
#define NB_  512
#define HID_ 1024
#define H_   16
#define D_   64
#define B_   8
#define Q_   2048

typedef unsigned short u16;
typedef float  f32x4  __attribute__((ext_vector_type(4)));
typedef short  short8 __attribute__((ext_vector_type(8)));

__device__ __forceinline__ u16 f2b_e22(float x) {
    __hip_bfloat16 h = __float2bfloat16(x);
    union { __hip_bfloat16 h; u16 u; } cv; cv.h = h; return cv.u;
}
__device__ __forceinline__ float b2f_e22(u16 u) {
    union { u16 u; __hip_bfloat16 h; } cv; cv.u = u; return __bfloat162float(cv.h);
}
__device__ __forceinline__ float ldin_e22(const void* p, long i, int bf) {
    return bf ? b2f_e22(((const u16*)p)[i]) : ((const float*)p)[i];
}

#define GLDSE22(gp, lp) __builtin_amdgcn_global_load_lds( \
    (const __attribute__((address_space(1))) void*)(gp), \
    (__attribute__((address_space(3))) void*)(lp), 16, 0, 0)

// ---------------------------------------------------------------------------
__global__ void probe_e22(const unsigned* __restrict__ k, int* __restrict__ flag)
{
    __shared__ int cnt;
    if (threadIdx.x == 0) cnt = 0;
    __syncthreads();
    int c = 0;
    for (int i = threadIdx.x; i < 4096; i += 256) {
        unsigned e = (k[i] >> 7) & 0xFFu;
        if (e >= 100u && e <= 135u) c++;
    }
    atomicAdd(&cnt, c);
    __syncthreads();
    if (threadIdx.x == 0) *flag = (cnt > 2048) ? 1 : 0;
}

__global__ void beacon_e22(float* __restrict__ out, long n, float code)
{
    long i = (long)blockIdx.x * blockDim.x + threadIdx.x;
    long st = (long)gridDim.x * blockDim.x;
    for (; i < n; i += st) out[i] = 0.f;
    if (blockIdx.x == 0 && threadIdx.x == 0) out[0] = code;
}

// ---------------------------------------------------------------------------
__global__ void conv_e22(const void* __restrict__ in, u16* __restrict__ out,
                         long n, const int* __restrict__ dflag)
{
    const int bf = *dflag;
    long i = (long)blockIdx.x * blockDim.x + threadIdx.x;
    long st = (long)gridDim.x * blockDim.x;
    for (; i < n; i += st) out[i] = f2b_e22(ldin_e22(in, i, bf));
}

// query (B,H,Q,64) -> qflat (B,Q,HID) bf16
__global__ void qg_e22(const void* __restrict__ q, u16* __restrict__ out,
                       const int* __restrict__ dflag)
{
    const int bf = *dflag;
    const long n = (long)B_ * H_ * Q_ * D_;
    long i = (long)blockIdx.x * blockDim.x + threadIdx.x;
    long st = (long)gridDim.x * blockDim.x;
    for (; i < n; i += st) {
        long dd = i & 63; long t = i >> 6;
        long qq = t & (Q_ - 1); t >>= 11;
        long h = t & (H_ - 1); long b = t >> 4;
        out[(b * Q_ + qq) * HID_ + h * 64 + dd] = f2b_e22(ldin_e22(q, i, bf));
    }
}

// fp32 -> hi + lo residual (bf16)   [proven]
__global__ void split_e22(const float* __restrict__ in, u16* __restrict__ hi,
                          u16* __restrict__ lo, long n)
{
    long i = (long)blockIdx.x * blockDim.x + threadIdx.x;
    long st = (long)gridDim.x * blockDim.x;
    for (; i < n; i += st) {
        float v = in[i];
        u16 h = f2b_e22(v);
        hi[i] = h;
        lo[i] = f2b_e22(v - b2f_e22(h));
    }
}

// transpose (proven): in (R,C) raw -> out (C,R) bf16
__global__ __launch_bounds__(256)
void tr_e22(const void* __restrict__ in, u16* __restrict__ out,
            int R, int C, long sIn, long sOut, const int* __restrict__ dflag)
{
    const int bf = *dflag;
    __shared__ u16 t[64][66];
    const long ibase = (long)blockIdx.z * sIn;
    u16* ob = out + (long)blockIdx.z * sOut;
    const int r0 = blockIdx.y * 64, c0 = blockIdx.x * 64;
    const int lc = threadIdx.x & 63, rb = threadIdx.x >> 6;
    #pragma unroll
    for (int kk = 0; kk < 16; ++kk) {
        int r = rb * 16 + kk;
        t[r][lc] = f2b_e22(ldin_e22(in, ibase + (long)(r0 + r) * C + c0 + lc, bf));
    }
    __syncthreads();
    #pragma unroll
    for (int kk = 0; kk < 16; ++kk) {
        int cr = rb * 16 + kk;
        ob[(long)(c0 + cr) * R + r0 + lc] = t[lc][cr];
    }
}

// elementwise mask epilogue (proven): km = kT * sigmoid(S + bmask), in place
__global__ void ew_e22(float* __restrict__ S, const u16* __restrict__ kT,
                       const void* __restrict__ bmask, const int* __restrict__ dflag)
{
    const int bf = *dflag;
    const long n = (long)B_ * HID_ * L_;
    long i = (long)blockIdx.x * blockDim.x + threadIdx.x;
    long st = (long)gridDim.x * blockDim.x;
    for (; i < n; i += st) {
        long m = i & (L_ - 1);
        float sg = 1.f / (1.f + expf(-(S[i] + ldin_e22(bmask, m, bf))));
        S[i] = b2f_e22(kT[i]) * sg;
    }
}

// ---------------------------------------------------------------------------
// MFMA GEMM (m97 structure, proven): C[M,N] = sum_k A[M,K]*Bt[N,K]
// epi: 3 = fp32 store (scale applied) ; 4 = fp32 accumulate
// ---------------------------------------------------------------------------
__global__ __launch_bounds__(256)
void gemm_e22(const u16* __restrict__ A, int lda, long sA,
              const u16* __restrict__ Bt, int ldb, long sB,
              float* __restrict__ Cv, int ldc, long sC, int K,
              float scale, int epi)
{
    __shared__ u16 As[128 * 32];
    __shared__ u16 Bs[128 * 32];
    const int tid = threadIdx.x;
    const int wv = tid >> 6, ln = tid & 63;
    const int g = ln >> 4, lr = ln & 15;
    const int wr = wv >> 1, wc = wv & 1;
    const int bm = blockIdx.y * 128, bn = blockIdx.x * 128;
    const u16* Ab = A + (long)blockIdx.z * sA;
    const u16* Bb = Bt + (long)blockIdx.z * sB;

    const int sr = ln >> 2;
    const int scl = (ln & 3) * 8;
    const u16* ga0 = Ab + (long)(bm + wv * 16 + sr) * lda + scl;
    const u16* ga1 = Ab + (long)(bm + (wv + 4) * 16 + sr) * lda + scl;
    const u16* gb0 = Bb + (long)(bn + wv * 16 + sr) * ldb + scl;
    const u16* gb1 = Bb + (long)(bn + (wv + 4) * 16 + sr) * ldb + scl;
    u16* la0 = &As[wv * 512];
    u16* la1 = &As[(wv + 4) * 512];
    u16* lb0 = &Bs[wv * 512];
    u16* lb1 = &Bs[(wv + 4) * 512];

    f32x4 acc[4][4];
    #pragma unroll
    for (int i = 0; i < 4; ++i)
        #pragma unroll
        for (int j = 0; j < 4; ++j) acc[i][j] = (f32x4){0.f, 0.f, 0.f, 0.f};

    for (int k0 = 0; k0 < K; k0 += 32) {
        GLDSE22(ga0 + k0, la0);
        GLDSE22(ga1 + k0, la1);
        GLDSE22(gb0 + k0, lb0);
        GLDSE22(gb1 + k0, lb1);
        __syncthreads();
        short8 af[4], bfr[4];
        #pragma unroll
        for (int i = 0; i < 4; ++i) af[i] = *(const short8*)&As[(wr * 64 + i * 16 + lr) * 32 + g * 8];
        #pragma unroll
        for (int j = 0; j < 4; ++j) bfr[j] = *(const short8*)&Bs[(wc * 64 + j * 16 + lr) * 32 + g * 8];
        #pragma unroll
        for (int i = 0; i < 4; ++i)
            #pragma unroll
            for (int j = 0; j < 4; ++j)
                acc[i][j] = __builtin_amdgcn_mfma_f32_16x16x32_bf16(af[i], bfr[j], acc[i][j], 0, 0, 0);
        __syncthreads();
    }

    // C/D layout (r4-verified): col = lane&15, row = (lane>>4)*4 + reg
    const int r0 = bm + wr * 64 + g * 4;
    const int c0 = bn + wc * 64 + lr;
    float* C = Cv + (long)blockIdx.z * sC;
    #pragma unroll
    for (int i = 0; i < 4; ++i)
        #pragma unroll
        for (int j = 0; j < 4; ++j)
            #pragma unroll
            for (int r = 0; r < 4; ++r) {
                long o = (long)(r0 + i * 16 + r) * ldc + (c0 + j * 16);
                if (epi == 4) C[o] += acc[i][j][r];
                else          C[o] = scale * acc[i][j][r];
            }
}

// ---------------------------------------------------------------------------
// G2 scalar fp32, 64x64 tile, 4x4 acc (same ascending-l order => bit-identical)
// Bmat[b][n][c] = sum_l gs[l][n] * km[b][c][l]
// grid (HID/64, NB/64, B) = 1024 blocks -> ~4 blocks/CU
// ---------------------------------------------------------------------------
__global__ __launch_bounds__(256)
void sg2c_e22(const float* __restrict__ kmF, const void* __restrict__ gs,
              float* __restrict__ BmatF, const int* __restrict__ dflag)
{
    const int bf = *dflag;
    __shared__ float gst[32][65];    // [l_off][n_off]
    __shared__ float kmt[64][33];    // [c_off][l_off]
    const int b = blockIdx.z;
    const int c0 = blockIdx.x * 64, n0 = blockIdx.y * 64;
    const int tid = threadIdx.x;
    const int tx = tid & 15, ty = tid >> 4;      // c = c0+tx+16i, n = n0+ty+16j
    float acc[4][4];
    #pragma unroll
    for (int i = 0; i < 4; ++i)
        #pragma unroll
        for (int j = 0; j < 4; ++j) acc[i][j] = 0.f;

    const int glc = tid & 63, grb = tid >> 6;    // gst loader: rows grb+4*kk
    const int klc = tid & 31, krb = tid >> 5;    // kmt loader: rows krb+8*kk
    for (int l0 = 0; l0 < L_; l0 += 32) {
        #pragma unroll
        for (int kk = 0; kk < 8; ++kk) {
            int r = grb + 4 * kk;                // [0,32)
            gst[r][glc] = ldin_e22(gs, (long)(l0 + r) * NB_ + n0 + glc, bf);
            int rr = krb + 8 * kk;               // [0,64)
            kmt[rr][klc] = kmF[((long)b * HID_ + c0 + rr) * L_ + l0 + klc];
        }
        __syncthreads();
        #pragma unroll 8
        for (int kk = 0; kk < 32; ++kk) {
            float gv[4], kv[4];
            #pragma unroll
            for (int j = 0; j < 4; ++j) gv[j] = gst[kk][ty + 16 * j];
            #pragma unroll
            for (int i = 0; i < 4; ++i) kv[i] = kmt[tx + 16 * i][kk];
            #pragma unroll
            for (int i = 0; i < 4; ++i)
                #pragma unroll
                for (int j = 0; j < 4; ++j)
                    acc[i][j] += kv[i] * gv[j];
        }
        __syncthreads();
    }
    #pragma unroll
    for (int j = 0; j < 4; ++j)
        #pragma unroll
        for (int i = 0; i < 4; ++i)
            BmatF[((long)b * NB_ + n0 + ty + 16 * j) * HID_ + c0 + tx + 16 * i] = acc[i][j];
}

// ---------------------------------------------------------------------------
// hoisted score reductions (proven verbatim)
// ---------------------------------------------------------------------------
__global__ void kw_e22(const float* __restrict__ keysF,
                       const void* __restrict__ w_mu, const void* __restrict__ w_sg,
                       float* __restrict__ kwmu, float* __restrict__ kwsg,
                       const int* __restrict__ dflag)
{
    const int bf = *dflag;
    const int bh = blockIdx.x;
    const int b = bh >> 4, h = bh & 15;
    const int d = threadIdx.x;
    const float* kb = keysF + (long)b * NB_ * HID_ + h * 64 + d;
    float am = 0.f, as = 0.f;
    for (int n = 0; n < NB_; ++n) {
        float kv = kb[(long)n * HID_];
        am += ldin_e22(w_mu, n, bf) * kv;
        as += ldin_e22(w_sg, n, bf) * kv;
    }
    kwmu[(long)bh * 64 + d] = am;
    kwsg[(long)bh * 64 + d] = as;
}

// ---------------------------------------------------------------------------
// attention: same math/order as proven attn_d21, but r stored TRANSPOSED
// rST[n][row] so PV reads one wave-uniform float4 (broadcast) per n.
// ---------------------------------------------------------------------------
__global__ __launch_bounds__(256)
void attn_e22(float* __restrict__ qh, const float* __restrict__ valsF,
              const float* __restrict__ kwmu, const float* __restrict__ kwsg,
              const void* __restrict__ bmu, const void* __restrict__ bsg,
              const int* __restrict__ dflag)
{
    const int bf = *dflag;
    __shared__ float bmuS[512], bvS[512];
    __shared__ float rST[512][16];              // [n][row] 32 KB
    const int b = blockIdx.z, h = blockIdx.y;
    const int tid = threadIdx.x, wv = tid >> 6, lane = tid & 63;

    for (int i = tid; i < 512; i += 256) {
        bmuS[i] = ldin_e22(bmu, i, bf);
        float s = ldin_e22(bsg, i, bf);
        bvS[i] = s * s;
    }
    __syncthreads();

    const int q0 = blockIdx.x * 16 + wv * 4;
    const float km = kwmu[((long)b * H_ + h) * 64 + lane];
    const float ks = kwsg[((long)b * H_ + h) * 64 + lane];

    float qv[4], mu[4], sq[4];
    float* qrow[4];
    #pragma unroll
    for (int j = 0; j < 4; ++j) {
        qrow[j] = qh + ((long)b * Q_ + q0 + j) * HID_ + h * 64;
        qv[j] = qrow[j][lane];
        float pm = qv[j] * km, ps = qv[j] * ks;
        #pragma unroll
        for (int off = 32; off > 0; off >>= 1) {
            pm += __shfl_xor(pm, off);
            ps += __shfl_xor(ps, off);
        }
        mu[j] = 1.f / (1.f + expf(-pm));
        float sp = (ps > 0.f) ? (ps + log1pf(expf(-ps))) : log1pf(expf(ps));
        sq[j] = fmaxf(sp, 1e-6f);
    }

    #pragma unroll
    for (int j = 0; j < 4; ++j) {
        #pragma unroll
        for (int jj = 0; jj < 8; ++jj) {
            int n = lane + 64 * jj;
            float var = sq[j] + bvS[n];
            float dd = mu[j] - bmuS[n];
            rST[n][wv * 4 + j] = expf(-0.5f * dd * dd / var)
                                 / sqrtf(6.283185307179586f * var);
        }
    }
    __syncthreads();

    const float* vb = valsF + (long)b * NB_ * HID_ + h * 64 + lane;
    float cd[4] = {0.f, 0.f, 0.f, 0.f};
    for (int n = 0; n < 512; ++n) {
        float v = vb[(long)n * HID_];
        const f32x4 r4 = *(const f32x4*)&rST[n][wv * 4];   // wave-uniform broadcast
        #pragma unroll
        for (int j = 0; j < 4; ++j)
            cd[j] += r4[j] * v;
    }
    #pragma unroll
    for (int j = 0; j < 4; ++j)
        qrow[j][lane] = cd[j];
}

// ---------------------------------------------------------------------------
extern "C" void kernel_launch(void* const* d_in, const int* in_sizes, int n_in,
                              void* d_out, int out_size, void* d_ws, size_t ws_size,
                              hipStream_t stream)
{
    static const int SZ_INS[13] = {16777216,16777216,4194304,2048,1048576,1048576,
                                   1048576,1048576,512,512,1048576,512,512};
    bool mi = (n_in == 13);
    if (mi) for (int i = 0; i < 13; ++i) if (in_sizes[i] != SZ_INS[i]) { mi = false; break; }
    if (!mi) {
        beacon_e22<<<2048, 256, 0, stream>>>((float*)d_out, (long)out_size, 7777777.f);
        return;
    }

    const void* k_in  = d_in[0];
    const void* query = d_in[1];
    const void* wm_f  = d_in[2];
    const void* bmask = d_in[3];
    const void* wq_f  = d_in[4];
    const void* wk_f  = d_in[5];
    const void* wv_f  = d_in[6];
    const void* wo_f  = d_in[7];
    const void* w_mu  = d_in[8];
    const void* w_sg  = d_in[9];
    const void* gs_f  = d_in[10];
    const void* bmu   = d_in[11];
    const void* bsg   = d_in[12];

    char* ws = (char*)d_ws;
    size_t off = 0;
    auto alloc = [&](size_t bytes) { char* p = ws + off; off += (bytes + 255) & ~(size_t)255; return p; };
    const size_t MiB = 1048576;
    const long SBH = (long)NB_ * HID_;
    const long SQH = (long)Q_ * HID_;
    const long SHL = (long)HID_ * L_;
    int*   dflag = (int*)alloc(256);
    char*  RQ    = alloc(64 * MiB);          // wmask[0:8)+kT[8:40) -> qhF/ctxF
    char*  SC    = alloc(64 * MiB);          // scores/kmF -> qflat[0:32)+bmh[32:40)+bml[40:48) -> ctxh/ctxl
    char*  BK    = alloc(16 * MiB);          // BmatF -> keysF
    float* valsF = (float*)alloc(16 * MiB);  // vals -> woc (after attn)
    u16*   wqc   = (u16*)alloc((size_t)HID_ * HID_ * 2);
    u16*   wkc   = (u16*)alloc((size_t)HID_ * HID_ * 2);
    u16*   wvc   = (u16*)alloc((size_t)HID_ * HID_ * 2);
    float* kwmu  = (float*)alloc((size_t)B_ * H_ * 64 * 4);
    float* kwsg  = (float*)alloc((size_t)B_ * H_ * 64 * 4);
    if (ws_size < off) {
        beacon_e22<<<2048, 256, 0, stream>>>((float*)d_out, (long)out_size, 9999999.f);
        return;
    }
    u16*   wmask = (u16*)RQ;                     // [0, 8MiB)
    u16*   kTp   = (u16*)(RQ + 8 * MiB);         // [8, 40MiB)
    float* qhF   = (float*)RQ;                   // after G1/ew (wmask,kT dead)
    float* ctxF  = qhF;
    float* SCf   = (float*)SC;                   // scores -> kmF (in place)
    u16*   qflat = (u16*)SC;                     // [0, 32MiB)   after sg2c
    u16*   bmh   = (u16*)(SC + 32 * MiB);        // [32, 40MiB)
    u16*   bml   = (u16*)(SC + 40 * MiB);        // [40, 48MiB)
    u16*   ctxh  = (u16*)SC;                     // [0, 32MiB)   after attn
    u16*   ctxl  = (u16*)(SC + 32 * MiB);        // [32, 64MiB)
    float* BmatF = (float*)BK;
    float* keysF = (float*)BK;                   // after split (BmatF dead)
    u16*   woc   = (u16*)valsF;                  // after attn (valsF dead)

    probe_e22<<<1, 256, 0, stream>>>((const unsigned*)k_in, dflag);
    conv_e22<<<1024, 256, 0, stream>>>(wq_f, wqc, (long)HID_ * HID_, dflag);
    conv_e22<<<1024, 256, 0, stream>>>(wk_f, wkc, (long)HID_ * HID_, dflag);
    conv_e22<<<1024, 256, 0, stream>>>(wv_f, wvc, (long)HID_ * HID_, dflag);
    conv_e22<<<2048, 256, 0, stream>>>(wm_f, wmask, (long)L_ * L_, dflag);
    tr_e22<<<dim3(HID_ / 64, L_ / 64, B_), 256, 0, stream>>>(
        k_in, kTp, L_, HID_, (long)L_ * HID_, SHL, dflag);

    // G1a (MFMA, proven): SC = kT @ wmask^T  (fp32 scores)
    gemm_e22<<<dim3(L_ / 128, HID_ / 128, B_), 256, 0, stream>>>(
        kTp, L_, SHL, wmask, L_, 0, SCf, L_, SHL, L_, 1.f, 3);
    // G1b (proven): km = kT * sigmoid(SC + bmask)  (in place)
    ew_e22<<<2048, 256, 0, stream>>>(SCf, kTp, bmask, dflag);

    // G2 (scalar fp32, 64x64 tiles, 1024 blocks): BmatF = Gs^T @ km
    sg2c_e22<<<dim3(HID_ / 64, NB_ / 64, B_), 256, 0, stream>>>(SCf, gs_f, BmatF, dflag);
    // split Bmat -> bmh/bml (kmF dead; writes SC[32:48))
    split_e22<<<2048, 256, 0, stream>>>(BmatF, bmh, bml, (long)B_ * SBH);

    // qflat gather into SC[0:32)
    qg_e22<<<4096, 256, 0, stream>>>(query, qflat, dflag);
    // G5 (MFMA, proven): qhF = 0.125 * qflat @ Wq^T  (over RQ; wmask/kT dead)
    gemm_e22<<<dim3(HID_ / 128, Q_ / 128, B_), 256, 0, stream>>>(
        qflat, HID_, SQH, wqc, HID_, 0, qhF, HID_, SQH, HID_, 0.125f, 3);

    // G3 (MFMA 2-pass, proven): keysF = bmh@Wk^T += bml@Wk^T  (over dead BmatF)
    gemm_e22<<<dim3(HID_ / 128, NB_ / 128, B_), 256, 0, stream>>>(
        bmh, HID_, SBH, wkc, HID_, 0, keysF, HID_, SBH, HID_, 1.f, 3);
    gemm_e22<<<dim3(HID_ / 128, NB_ / 128, B_), 256, 0, stream>>>(
        bml, HID_, SBH, wkc, HID_, 0, keysF, HID_, SBH, HID_, 1.f, 4);
    kw_e22<<<B_ * H_, 64, 0, stream>>>(keysF, w_mu, w_sg, kwmu, kwsg, dflag);

    // G4 (MFMA 2-pass, proven): valsF = bmh@Wv^T += bml@Wv^T
    gemm_e22<<<dim3(HID_ / 128, NB_ / 128, B_), 256, 0, stream>>>(
        bmh, HID_, SBH, wvc, HID_, 0, valsF, HID_, SBH, HID_, 1.f, 3);
    gemm_e22<<<dim3(HID_ / 128, NB_ / 128, B_), 256, 0, stream>>>(
        bml, HID_, SBH, wvc, HID_, 0, valsF, HID_, SBH, HID_, 1.f, 4);

    // attention (same math, transposed-r PV): ctx in place over qhF
    attn_e22<<<dim3(Q_ / 16, H_, B_), 256, 0, stream>>>(
        qhF, valsF, kwmu, kwsg, bmu, bsg, dflag);

    // G7 (MFMA 2-pass, proven): split ctx, out = ctxh@Wo^T += ctxl@Wo^T
    conv_e22<<<1024, 256, 0, stream>>>(wo_f, woc, (long)HID_ * HID_, dflag);
    split_e22<<<2048, 256, 0, stream>>>(ctxF, ctxh, ctxl, (long)B_ * SQH);
    gemm_e22<<<dim3(HID_ / 128, Q_ / 128, B_), 256, 0, stream>>>(
        ctxh, HID_, SQH, woc, HID_, 0, (float*)d_out, HID_, SQH, HID_, 1.f, 3);
    gemm_e22<<<dim3(HID_ / 128, Q_ / 128, B_), 256, 0, stream>>>(
        ctxl, HID_, SQH, woc, HID_, 0, (float*)d_out, HID_, SQH, HID_, 1.f, 4);
}